// Round 5
// baseline (306.308 us; speedup 1.0000x reference)
//
#include <hip/hip_runtime.h>

#define BATCH 4096
#define TT 512
#define HH 64
#define BT 4       // batch rows per block; batch j at MFMA tile row 4j -> lane's valid C/D slot is r=0
#define XS 516     // x_s row stride in floats
#define HS 72      // h buffer row stride in bf16

typedef __attribute__((ext_vector_type(8))) short short8;
typedef __attribute__((ext_vector_type(4))) float floatx4;

__device__ __forceinline__ unsigned short f2bf(float f) {   // RNE f32->bf16
    unsigned u = __float_as_uint(f);
    u = u + 0x7FFFu + ((u >> 16) & 1u);
    return (unsigned short)(u >> 16);
}

// 256 threads = 4 waves; grid 1024 = 4 independent blocks/CU. Wave w owns gate
// col-tiles {w,w+4,w+8,w+12}; each lane activates one (batch q, hidden n) cell.
// Activation math merged to 5 exp + 2 rcp per cell (was 10 trans):
//   c' = [c*(1+ei)(1+eg) + (eg-1)(1+ef)] * rcp((1+ef)(1+ei)(1+eg))
//   h  = (ec-1) * rcp((1+eo)(1+ec))
__global__ __launch_bounds__(256, 4) void lstm_kernel(
    const float* __restrict__ x, const float* __restrict__ W_ih,
    const float* __restrict__ W_hh, const float* __restrict__ b_ih,
    const float* __restrict__ b_hh, const float* __restrict__ W_out,
    const float* __restrict__ b_out, float* __restrict__ out)
{
    __shared__ __align__(16) float x_s[BT * XS];
    __shared__ __align__(16) unsigned short hb0[16 * HS];   // rows m%4!=0 stay 0
    __shared__ __align__(16) unsigned short hb1[16 * HS];
    __shared__ __align__(16) float hf[BT * 65];

    const int tid = threadIdx.x;
    const int w = tid >> 6;
    const int l = tid & 63;
    const int q = l >> 4;         // lane's batch row (0..3)
    const int c = l & 15;
    const int n = 16 * w + c;     // lane's hidden index
    const int bbase = blockIdx.x * BT;

    // stage x[bbase..bbase+3][0..511] into LDS, coalesced float4
    for (int i = 0; i < 2; ++i) {
        int flat = i * 256 + tid;
        int row = flat >> 7, c4 = flat & 127;
        const float4* xg = reinterpret_cast<const float4*>(x + (size_t)(bbase + row) * TT);
        float4 v = xg[c4];
        *reinterpret_cast<float4*>(&x_s[row * XS + c4 * 4]) = v;
    }
    for (int i = tid; i < 16 * HS; i += 256) { hb0[i] = 0; hb1[i] = 0; }

    // persistent B-fragments: W_hh rows for gates g = 64*t + n, bf16
    short8 bfr[4][2];
    float wih[4], bb[4];
    for (int t = 0; t < 4; ++t) {
        int g = 64 * t + n;
        wih[t] = W_ih[g];
        bb[t] = b_ih[g] + b_hh[g];
        for (int ks = 0; ks < 2; ++ks) {
            const float* wp = W_hh + g * 64 + ks * 32 + q * 8;
            short8 v;
            #pragma unroll
            for (int j = 0; j < 8; ++j) v[j] = (short)f2bf(wp[j]);
            bfr[t][ks] = v;
        }
    }

    float cst = 0.f;              // c-state for (batch q, hidden n)
    float hv = 0.f;               // last h (register; written to hf after loop)
    floatx4 acc[4];               // slots 1..3 garbage rows: zero-init once, never touched
    #pragma unroll
    for (int t = 0; t < 4; ++t) acc[t] = floatx4{0.f, 0.f, 0.f, 0.f};

    const int aoff = c * HS + q * 8;      // A-frag LDS offset (shorts), hoisted
    const int woff = (4 * q) * HS + n;    // h write offset, hoisted
    const float* xrow = &x_s[q * XS];
    const float L1 = 1.44269504089f;      // log2(e)
    const float L2 = 2.88539008178f;      // 2*log2(e)

    __syncthreads();

    auto step = [&](const unsigned short* __restrict__ src,
                    unsigned short* __restrict__ dst, float xv) {
        short8 a0 = *reinterpret_cast<const short8*>(src + aoff);
        short8 a1 = *reinterpret_cast<const short8*>(src + aoff + 32);
        #pragma unroll
        for (int t = 0; t < 4; ++t) acc[t][0] = fmaf(xv, wih[t], bb[t]);
        #pragma unroll
        for (int t = 0; t < 4; ++t) {
            acc[t] = __builtin_amdgcn_mfma_f32_16x16x32_bf16(a0, bfr[t][0], acc[t], 0, 0, 0);
            acc[t] = __builtin_amdgcn_mfma_f32_16x16x32_bf16(a1, bfr[t][1], acc[t], 0, 0, 0);
        }
        float gi = acc[0][0], gf = acc[1][0], gg = acc[2][0], go = acc[3][0];
        float ei = __builtin_amdgcn_exp2f(-L1 * gi);
        float ef = __builtin_amdgcn_exp2f(-L1 * gf);
        float eg = __builtin_amdgcn_exp2f( L2 * gg);
        float eo = __builtin_amdgcn_exp2f(-L1 * go);
        float pf1 = 1.f + ef, pi1 = 1.f + ei, pg1 = 1.f + eg, po1 = 1.f + eo;
        float pig = pi1 * pg1;
        float num = fmaf(cst, pig, (eg - 1.f) * pf1);
        cst = num * __builtin_amdgcn_rcpf(pf1 * pig);
        float ec = __builtin_amdgcn_exp2f(L2 * cst);
        hv = (ec - 1.f) * __builtin_amdgcn_rcpf(po1 * (1.f + ec));
        dst[woff] = f2bf(hv);
        __syncthreads();
    };

    for (int ts4 = 0; ts4 < TT; ts4 += 4) {
        float4 xq = *reinterpret_cast<const float4*>(xrow + ts4);
        step(hb0, hb1, xq.x);
        step(hb1, hb0, xq.y);
        step(hb0, hb1, xq.z);
        step(hb1, hb0, xq.w);
    }

    hf[q * 65 + n] = hv;
    __syncthreads();

    // head: out[b][o] = sum_n hf[b][n]*W_out[o][n] + b_out[o]
    if (tid < BT * 3) {
        int row = tid / 3, o = tid % 3;
        float s = b_out[o];
        #pragma unroll 8
        for (int k = 0; k < HH; ++k) s = fmaf(hf[row * 65 + k], W_out[o * 64 + k], s);
        out[(size_t)(bbase + row) * 3 + o] = s;
    }
}

extern "C" void kernel_launch(void* const* d_in, const int* in_sizes, int n_in,
                              void* d_out, int out_size, void* d_ws, size_t ws_size,
                              hipStream_t stream) {
    const float* x     = (const float*)d_in[0];
    const float* W_ih  = (const float*)d_in[1];
    const float* W_hh  = (const float*)d_in[2];
    const float* b_ih  = (const float*)d_in[3];
    const float* b_hh  = (const float*)d_in[4];
    const float* W_out = (const float*)d_in[5];
    const float* b_out = (const float*)d_in[6];
    float* out = (float*)d_out;
    hipLaunchKernelGGL(lstm_kernel, dim3(BATCH / BT), dim3(256), 0, stream,
                       x, W_ih, W_hh, b_ih, b_hh, W_out, b_out, out);
}